// Round 13
// baseline (166.194 us; speedup 1.0000x reference)
//
#include <hip/hip_runtime.h>
#include <hip/hip_bf16.h>

#define HID  128
#define NRAD 16
#define NT   100      // atom types (emb rows)

// LDS (dynamic, 147008 B -> 1 block/CU):
//   Pl  : f32 [NT][260] (260-stride -> 8-bank spread on random rows) 104000 B
//   rb  : 8 x [16 edges][256 B] per-wave swizzled r slabs             32768 B
//   WrL : bf16 [128][40] Wrbf+bias, padded rows (16B-aligned b128)    10240 B
#define PL_BYTES   (NT * 260 * 4)          // 104000
#define RB_OFF     PL_BYTES
#define WR_OFF     (RB_OFF + 8 * 4096)     // 136768
#define WR_BYTES   (HID * 40 * 2)          // 10240
#define LDS_BYTES  (WR_OFF + WR_BYTES)     // 147008

// Workspace: P f32 [NT][260] | W3 bf16 [128][128] | Wr40 bf16 [128][40]
#define WS_W3_OFF  PL_BYTES
#define WS_WR_OFF  (WS_W3_OFF + HID * HID * 2)

typedef __attribute__((ext_vector_type(4))) float f32x4;
typedef __attribute__((ext_vector_type(8))) __bf16 bf16x8;
typedef __attribute__((ext_vector_type(4))) __bf16 bf16x4;

union F8 { bf16x8 b; int4 i4; };
union B4 { bf16x4 b4; int2 i2; };

__device__ inline unsigned short f2bfbits(float f){
  unsigned int u = __float_as_uint(f);
  u += 0x7FFFu + ((u >> 16) & 1u);
  return (unsigned short)(u >> 16);
}

__device__ inline float silu_f(float v){
  return v * __builtin_amdgcn_rcpf(1.0f + __expf(-v));
}

// ---------------------------------------------------------------------------
// Setup (one launch):
//   blocks [0, ntypes)      : P[t][0:128]=emb@W1^T+b_lin ; [128:256]=emb@W2^T
//                             (rows padded to 260 f32, pad zeroed)
//   blocks [ntypes, +64)    : W3 bf16 row-major (consumed into registers)
//   blocks [ntypes+64, +20) : Wr40 bf16 [128][40]: cols0-15=W_rbf,
//                             col16=b_rbf, cols17-39=0
// ---------------------------------------------------------------------------
__global__ void setup_kernel(const float* __restrict__ emb,
                             const float* __restrict__ W_lin,
                             const float* __restrict__ b_lin,
                             const float* __restrict__ W_rbf,
                             const float* __restrict__ b_rbf,
                             int ntypes,
                             float* __restrict__ P,
                             unsigned short* __restrict__ W3,
                             unsigned short* __restrict__ Wr40){
  int blk = blockIdx.x;
  int n = threadIdx.x;                // 0..255
  if (blk < ntypes){
    __shared__ float er[HID];
    if (n < HID) er[n] = emb[blk * HID + n];
    __syncthreads();
    int half = n >> 7, nn = n & 127;
    const float4* w4 = (const float4*)(W_lin + (size_t)nn * (3 * HID) + half * HID);
    float s = half ? 0.0f : b_lin[nn];
    #pragma unroll 8
    for (int k4 = 0; k4 < HID / 4; ++k4){
      float4 w = w4[k4];
      s += er[k4*4+0]*w.x + er[k4*4+1]*w.y + er[k4*4+2]*w.z + er[k4*4+3]*w.w;
    }
    P[blk * 260 + n] = s;
    if (n < 4) P[blk * 260 + 256 + n] = 0.f;   // deterministic pad
  } else if (blk < ntypes + 64){
    int idx = (blk - ntypes) * 256 + n;        // 0..16383
    int r = idx >> 7, k = idx & 127;
    W3[idx] = f2bfbits(W_lin[(size_t)r * (3 * HID) + 2 * HID + k]);
  } else {
    int idx = (blk - ntypes - 64) * 256 + n;   // 0..5119
    int r = idx / 40, k = idx % 40;
    float v = (k < 16) ? W_rbf[r * NRAD + k] : (k == 16 ? b_rbf[r] : 0.f);
    Wr40[idx] = f2bfbits(v);
  }
}

// ---------------------------------------------------------------------------
// Edge kernel: 512 threads (8 waves), WAVE-LOCAL streaming, NO barriers.
// Each wave owns an independent grid-stride stream of 16-edge slabs:
//   phase 1: r = silu(rbf@Wrbf^T + b) (bias via augmented k=16 column;
//            Wrbf A-fragments read from padded LDS) -> own 4 KB swizzled slab
//   phase 2: acc = W3 * r^T with the FULL W3 held in 128 VGPRs (loaded once;
//            Wrbf moved to LDS keeps total VGPR ~210 < 256 — the R8 fix)
//   epilogue: out = silu(acc + P1[x[i]] + P2[x[j]]), P f32 in LDS @260-stride
// Stores stream continuously -> HBM-write drain overlaps LDS/compute.
// Per-lane 1-ahead prefetch of ei/ej/rbf; x-gathers issued after phase 1.
// ---------------------------------------------------------------------------
__global__ __launch_bounds__(512, 2) void edge_kernel(
    const float* __restrict__ rbf,
    const int*   __restrict__ ei,
    const int*   __restrict__ ej,
    const int*   __restrict__ x,
    const float* __restrict__ Pg,             // f32 [NT][260]
    const unsigned short* __restrict__ W3,    // bf16 [128][128]
    const unsigned short* __restrict__ Wr40,  // bf16 [128][40]
    float* __restrict__ out,
    int E, int nslab)
{
  extern __shared__ char smem[];
  const float* Pl = (const float*)smem;

  const int tid  = threadIdx.x;
  const int lane = tid & 63;
  const int wv   = tid >> 6;        // 0..7
  const int erow = lane & 15;       // edge-within-slab AND W-row index
  const int kgrp = lane >> 4;       // 0..3
  char* rbw = smem + RB_OFF + wv * 4096;     // this wave's private r slab
  const unsigned short* WrL = (const unsigned short*)(smem + WR_OFF);
  const int swz = (erow & 7) << 4;

  // ---- stage P and Wr40 into LDS ------------------------------------------
  for (int i = tid; i < PL_BYTES / 16; i += 512)
    ((int4*)smem)[i] = ((const int4*)Pg)[i];
  for (int i = tid; i < WR_BYTES / 16; i += 512)
    ((int4*)(smem + WR_OFF))[i] = ((const int4*)Wr40)[i];

  // ---- FULL W3 into registers (128 VGPR, loaded once) ---------------------
  F8 w3r[32];
  #pragma unroll
  for (int t = 0; t < 8; ++t)
    #pragma unroll
    for (int s = 0; s < 4; ++s)
      w3r[t * 4 + s].i4 = *(const int4*)(W3 + (t * 16 + erow) * HID + s * 32 + kgrp * 8);

  const int stride = gridDim.x * 8;
  int slab = blockIdx.x * 8 + wv;

  // ---- prologue: first slab's indices + rbf -------------------------------
  int xa = 0, xb = 0;
  f32x4 f0 = {0,0,0,0}, f1 = {0,0,0,0};
  if (slab < nslab){
    long ge = (long)slab * 16 + erow; if (ge > (long)E - 1) ge = E - 1;
    xa = x[ei[ge]];
    xb = x[ej[ge]];
    if (kgrp < 2){
      const f32x4* s4 = (const f32x4*)(rbf + ge * NRAD + kgrp * 8);
      f0 = __builtin_nontemporal_load(s4);
      f1 = __builtin_nontemporal_load(s4 + 1);
    }
  }

  __syncthreads();                             // tables staged (only barrier)

  while (slab < nslab){
    const long ge   = (long)slab * 16 + erow;
    const int  next = slab + stride;

    // ---- issue next slab's ei/ej + rbf loads ------------------------------
    int nei = 0, nej = 0;
    f32x4 nf0 = {0,0,0,0}, nf1 = {0,0,0,0};
    if (next < nslab){
      long gn = (long)next * 16 + erow;
      nei = ei[gn];
      nej = ej[gn];
      if (kgrp < 2){
        const f32x4* s4 = (const f32x4*)(rbf + gn * NRAD + kgrp * 8);
        nf0 = __builtin_nontemporal_load(s4);
        nf1 = __builtin_nontemporal_load(s4 + 1);
      }
    }

    // ---- phase 1: r for own 16 edges -> own swizzled slab -----------------
    F8 fb; fb.i4 = make_int4(0, 0, 0, 0);
    if (kgrp < 2){
      fb.b[0]=(__bf16)f0.x; fb.b[1]=(__bf16)f0.y; fb.b[2]=(__bf16)f0.z; fb.b[3]=(__bf16)f0.w;
      fb.b[4]=(__bf16)f1.x; fb.b[5]=(__bf16)f1.y; fb.b[6]=(__bf16)f1.z; fb.b[7]=(__bf16)f1.w;
    } else if (kgrp == 2){
      fb.b[0] = (__bf16)1.0f;                  // bias column (k=16)
    }
    #pragma unroll
    for (int t = 0; t < 8; ++t){
      F8 fa; fa.i4 = *(const int4*)(WrL + (t * 16 + erow) * 40 + kgrp * 8);
      f32x4 acc = {0.f, 0.f, 0.f, 0.f};
      acc = __builtin_amdgcn_mfma_f32_16x16x32_bf16(fa.b, fb.b, acc, 0, 0, 0);
      B4 pk;                                   // D: col=edge erow, row=kgrp*4+r
      pk.b4[0] = (__bf16)silu_f(acc[0]);
      pk.b4[1] = (__bf16)silu_f(acc[1]);
      pk.b4[2] = (__bf16)silu_f(acc[2]);
      pk.b4[3] = (__bf16)silu_f(acc[3]);
      int byte = (erow << 8) + t * 32 + kgrp * 8;
      byte ^= swz;
      *(int2*)(rbw + byte) = pk.i2;
    }

    // ---- next slab's x-gathers (ei/ej loads have landed under phase 1) ----
    int nxa = 0, nxb = 0;
    if (next < nslab){ nxa = x[nei]; nxb = x[nej]; }

    // wave-local RAW on rbw: DS pipe is in-order per wave; drain before reads
    asm volatile("s_waitcnt lgkmcnt(0)" ::: "memory");
    __builtin_amdgcn_sched_barrier(0);

    // ---- phase 2: acc = W3 * r^T (W3 from registers) ----------------------
    f32x4 acc2[8];
    #pragma unroll
    for (int t = 0; t < 8; ++t) acc2[t] = (f32x4){0.f, 0.f, 0.f, 0.f};

    #pragma unroll
    for (int s = 0; s < 4; ++s){
      int rbyte = ((erow << 8) + s * 64 + kgrp * 16) ^ swz;
      F8 bB; bB.i4 = *(const int4*)(rbw + rbyte);          // B: col=edge erow
      #pragma unroll
      for (int t = 0; t < 8; ++t)
        acc2[t] = __builtin_amdgcn_mfma_f32_16x16x32_bf16(w3r[t*4+s].b, bB.b, acc2[t], 0, 0, 0);
    }

    // ---- epilogue: lane owns edge ge, n = t*16 + kgrp*4 + (0..3) ----------
    const float* pa = Pl + xa * 260;
    const float* pb = Pl + xb * 260 + 128;
    #pragma unroll
    for (int t = 0; t < 8; ++t){
      const int nb = t * 16 + kgrp * 4;
      f32x4 p1 = *(const f32x4*)(pa + nb);
      f32x4 p2 = *(const f32x4*)(pb + nb);
      f32x4 o;
      o.x = silu_f(acc2[t][0] + p1.x + p2.x);
      o.y = silu_f(acc2[t][1] + p1.y + p2.y);
      o.z = silu_f(acc2[t][2] + p1.z + p2.z);
      o.w = silu_f(acc2[t][3] + p1.w + p2.w);
      if (ge < E)
        *(f32x4*)(out + ge * HID + nb) = o;
    }

    // ---- rotate pipeline ---------------------------------------------------
    f0 = nf0; f1 = nf1; xa = nxa; xb = nxb;
    slab = next;
  }
}

// ---------------------------------------------------------------------------
extern "C" void kernel_launch(void* const* d_in, const int* in_sizes, int n_in,
                              void* d_out, int out_size, void* d_ws, size_t ws_size,
                              hipStream_t stream){
  const int*   x    = (const int*)  d_in[0];
  const float* rbf  = (const float*)d_in[1];
  const int*   ei   = (const int*)  d_in[2];
  const int*   ej   = (const int*)  d_in[3];
  const float* emb  = (const float*)d_in[4];
  const float* Wrbf = (const float*)d_in[5];
  const float* brbf = (const float*)d_in[6];
  const float* Wlin = (const float*)d_in[7];
  const float* blin = (const float*)d_in[8];
  float* out = (float*)d_out;

  const int E      = in_sizes[2];
  const int ntypes = in_sizes[4] / HID;   // 100

  float*          P    = (float*)d_ws;
  unsigned short* W3   = (unsigned short*)((char*)d_ws + WS_W3_OFF);
  unsigned short* Wr40 = (unsigned short*)((char*)d_ws + WS_WR_OFF);

  setup_kernel<<<ntypes + 64 + 20, 256, 0, stream>>>(
      emb, Wlin, blin, Wrbf, brbf, ntypes, P, W3, Wr40);

  (void)hipFuncSetAttribute(reinterpret_cast<const void*>(&edge_kernel),
                            hipFuncAttributeMaxDynamicSharedMemorySize, LDS_BYTES);

  const int nslab = (E + 15) / 16;
  edge_kernel<<<256, 512, LDS_BYTES, stream>>>(
      rbf, ei, ej, x, P, W3, Wr40, out, E, nslab);
}